// Round 2
// baseline (72.589 us; speedup 1.0000x reference)
//
#include <hip/hip_runtime.h>
#include <hip/hip_bf16.h>

// Problem constants (match reference)
#define NSIDE    256
#define NFACETS  786432          // 12*256*256

// ---------- bf16 helpers (bit-level, RNE) ----------
__device__ __forceinline__ unsigned short f2bf(float f) {
    unsigned u = __float_as_uint(f);
    u += 0x7FFFu + ((u >> 16) & 1u);      // round-to-nearest-even
    return (unsigned short)(u >> 16);
}
__device__ __forceinline__ float bf2f(unsigned short h) {
    return __uint_as_float(((unsigned)h) << 16);
}

// ---------- HEALPix nested pix2vec, nside=256 ----------
__device__ __forceinline__ unsigned compress_bits(unsigned v) {
    v &= 0x55555555u;
    v = (v | (v >> 1)) & 0x33333333u;
    v = (v | (v >> 2)) & 0x0F0F0F0Fu;
    v = (v | (v >> 4)) & 0x00FF00FFu;
    v = (v | (v >> 8)) & 0x0000FFFFu;
    return v;
}

__device__ __forceinline__ float3 pix2vec_nest256(int pix) {
    int face = pix >> 16;                 // npface = 65536
    unsigned ipf = (unsigned)(pix & 0xFFFF);
    int ix = (int)compress_bits(ipf);
    int iy = (int)compress_bits(ipf >> 1);
    int jrll = 2 + (face >> 2);                           // {2,3,4}
    int jpll = 2 * (face & 3) + (((face >> 2) == 1) ? 0 : 1); // {1,3,5,7,0,2,4,6,1,3,5,7}
    int jr = jrll * NSIDE - ix - iy - 1;
    bool north = jr < NSIDE;
    bool south = jr > 3 * NSIDE;
    int nr = north ? jr : (south ? 4 * NSIDE - jr : NSIDE);
    const float fact2 = 4.0f / (12.0f * (float)NSIDE * (float)NSIDE);
    const float fact1 = (2.0f * (float)NSIDE) * fact2;
    float nrf = (float)nr;
    float z;
    if (north)      z = 1.0f - nrf * nrf * fact2;
    else if (south) z = nrf * nrf * fact2 - 1.0f;
    else            z = (float)(2 * NSIDE - jr) * fact1;
    int kshift = (north || south) ? 0 : (jr & 1);
    int num = jpll * nr + ix - iy + 1 + kshift;
    int jp = num / 2;                     // C-style trunc division, matches reference
    if (jp > 4 * nr) jp -= 4 * nr;
    if (jp < 1)      jp += 4 * nr;
    float phi = ((float)jp - ((float)kshift + 1.0f) * 0.5f) * (1.5707963267948966f / nrf);
    float sth = sqrtf((1.0f - z) * (1.0f + z));
    float sp, cp;
    __sincosf(phi, &sp, &cp);
    float3 r;
    r.x = sth * cp;
    r.y = sth * sp;
    r.z = z;
    return r;
}

// ---------- kernel 1: build per-facet payload table ----------
// table[f0] = {bf16 x, y, z, score} for every img0 facet with a correspondence.
// Non-member facets stay zero (memset), which exactly reproduces the mask=0 path
// (s=0 children contribute nothing to COG).
__global__ __launch_bounds__(256)
void build_table_kernel(const int* __restrict__ corr,
                        const int* __restrict__ f0s,
                        const int* __restrict__ f1s,
                        const float* __restrict__ kps,
                        ushort4* __restrict__ table,
                        int n0) {
    int i = blockIdx.x * blockDim.x + threadIdx.x;
    if (i >= n0) return;
    int f0 = f0s[i];
    int j  = corr[i];
    // lut_corr[0]=0 override: facet 0 maps to pixel 0
    int a = (f0 == 0) ? 0 : f1s[j];
    // lut_kpt[0]=0 override
    int b = (a == 0) ? 0 : j;
    float sc = kps[b];
    float3 v = pix2vec_nest256(a);
    ushort4 e;
    e.x = f2bf(v.x);
    e.y = f2bf(v.y);
    e.z = f2bf(v.z);
    e.w = f2bf(sc);
    table[f0] = e;   // f0 values are unique -> race-free
}

// ---------- kernel 2: COG over groups of 4 children ----------
__global__ __launch_bounds__(256)
void cog_kernel(const int4* __restrict__ filt4,
                const ushort4* __restrict__ table,
                float* __restrict__ out,
                int P, int score_off) {
    int p = blockIdx.x * blockDim.x + threadIdx.x;
    if (p >= P) return;
    int4 f = filt4[p];
    ushort4 e0 = table[f.x];
    ushort4 e1 = table[f.y];
    ushort4 e2 = table[f.z];
    ushort4 e3 = table[f.w];
    float s0 = bf2f(e0.w), s1 = bf2f(e1.w), s2 = bf2f(e2.w), s3 = bf2f(e3.w);
    float den = s0 + s1 + s2 + s3;
    float px = s0 * bf2f(e0.x) + s1 * bf2f(e1.x) + s2 * bf2f(e2.x) + s3 * bf2f(e3.x);
    float py = s0 * bf2f(e0.y) + s1 * bf2f(e1.y) + s2 * bf2f(e2.y) + s3 * bf2f(e3.y);
    float pz = s0 * bf2f(e0.z) + s1 * bf2f(e1.z) + s2 * bf2f(e2.z) + s3 * bf2f(e3.z);
    int cnt = (int)(s0 > 0.f) + (int)(s1 > 0.f) + (int)(s2 > 0.f) + (int)(s3 > 0.f);
    float ox = 0.f, oy = 0.f, oz = 0.f, osc = 0.f;
    if (den != 0.f) {
        float inv = 1.0f / den;
        ox = px * inv; oy = py * inv; oz = pz * inv;
        // cnt > 0 guaranteed when den > 0; branchless reciprocal of count
        float rcp = (cnt == 1) ? 1.f : (cnt == 2) ? 0.5f : (cnt == 3) ? (1.f / 3.f) : 0.25f;
        osc = den * rcp;
    }
    out[3 * p + 0] = ox;
    out[3 * p + 1] = oy;
    out[3 * p + 2] = oz;
    out[score_off + p] = osc;
}

// ---------- kernel 3: passthrough tail outputs ----------
__global__ __launch_bounds__(256)
void tail_kernel(const int* __restrict__ corr,
                 const float* __restrict__ kps,
                 float* __restrict__ out,
                 int n0, int n1,
                 int idx0_off, int idx1_off, int kps_off) {
    int i = blockIdx.x * blockDim.x + threadIdx.x;
    if (i < n0) {
        out[idx0_off + i] = (float)i;
        out[idx1_off + i] = (float)corr[i];
    }
    if (i < n1) {
        out[kps_off + i] = kps[i];
    }
}

extern "C" void kernel_launch(void* const* d_in, const int* in_sizes, int n_in,
                              void* d_out, int out_size, void* d_ws, size_t ws_size,
                              hipStream_t stream) {
    // inputs (setup_inputs order):
    // 0: nside (scalar int)        1: correspondences [1,N0] int32
    // 2: img0_child_facets [1,N0]  3: img1_child_facets [1,N1] int32
    // 4: filt [M] int32            5: keypointScores1 [1,N1] float32
    const int* corr = (const int*)d_in[1];
    const int* f0s  = (const int*)d_in[2];
    const int* f1s  = (const int*)d_in[3];
    const int* filt = (const int*)d_in[4];
    const float* kps = (const float*)d_in[5];

    const int n0 = in_sizes[1];
    const int n1 = in_sizes[5];
    const int M  = in_sizes[4];
    const int P  = M / 4;

    // output layout (flat float32, reference return order):
    // [0, 3P) pos_cog | [3P, 4P) score_cog | [4P, 4P+n0) idx0 |
    // [4P+n0, 4P+2n0) idx1 | [4P+2n0, 4P+2n0+n1) keypointScores1
    const int score_off = 3 * P;
    const int idx0_off  = 4 * P;
    const int idx1_off  = idx0_off + n0;
    const int kps_off   = idx1_off + n0;

    ushort4* table = (ushort4*)d_ws;                 // NFACETS * 8 bytes = 6.29 MB
    float* out = (float*)d_out;

    hipMemsetAsync(d_ws, 0, (size_t)NFACETS * sizeof(ushort4), stream);

    int b = 256;
    build_table_kernel<<<(n0 + b - 1) / b, b, 0, stream>>>(corr, f0s, f1s, kps, table, n0);
    cog_kernel<<<(P + b - 1) / b, b, 0, stream>>>((const int4*)filt, table, out, P, score_off);
    int ntail = (n0 > n1) ? n0 : n1;
    tail_kernel<<<(ntail + b - 1) / b, b, 0, stream>>>(corr, kps, out, n0, n1,
                                                      idx0_off, idx1_off, kps_off);
}

// Round 3
// 44.653 us; speedup vs baseline: 1.6256x; 1.6256x over previous
//
#include <hip/hip_runtime.h>
#include <hip/hip_bf16.h>

#define NSIDE    256
#define NFACETS  786432          // 12*256*256

typedef int vint4 __attribute__((ext_vector_type(4)));

// ---------- 12-bit mini-float score codec (5-bit exp bias 95->[2^-31,1], 7-bit mant, RNE) ----------
// Invariant: code==0  <=>  s==0, so the (s>0) predicate and den==0 path match the reference.
__device__ __forceinline__ unsigned encode_score(float s) {
    if (s <= 0.f) return 0u;                    // scores are >= 0
    unsigned u = __float_as_uint(s);
    u += 0x8000u + ((u >> 16) & 1u);            // RNE to 7-bit mantissa
    int e = (int)((u >> 23) & 0xFFu);
    unsigned m = (u >> 16) & 0x7Fu;
    int field = e - 95;                         // e in [96,126] -> [1,31]
    if (field < 1)  { field = 1; m = 0u; }      // clamp tiny (keeps >0)
    if (field > 31) { field = 31; m = 127u; }   // clamp ~1.0 (rounding overflow)
    return ((unsigned)field << 7) | m;
}
__device__ __forceinline__ float decode_score(unsigned c) {
    if (c == 0u) return 0.f;
    unsigned field = (c >> 7) & 0x1Fu;
    unsigned m = c & 0x7Fu;
    return __uint_as_float(((field + 95u) << 23) | (m << 16));
}

// ---------- HEALPix nested pix2vec, nside=256 ----------
__device__ __forceinline__ unsigned compress_bits(unsigned v) {
    v &= 0x55555555u;
    v = (v | (v >> 1)) & 0x33333333u;
    v = (v | (v >> 2)) & 0x0F0F0F0Fu;
    v = (v | (v >> 4)) & 0x00FF00FFu;
    v = (v | (v >> 8)) & 0x0000FFFFu;
    return v;
}

__device__ __forceinline__ float3 pix2vec_nest256(int pix) {
    int face = pix >> 16;                 // npface = 65536
    unsigned ipf = (unsigned)(pix & 0xFFFF);
    int ix = (int)compress_bits(ipf);
    int iy = (int)compress_bits(ipf >> 1);
    int jrll = 2 + (face >> 2);                               // {2,3,4}
    int jpll = 2 * (face & 3) + (((face >> 2) == 1) ? 0 : 1); // {1,3,5,7,0,2,4,6,1,3,5,7}
    int jr = jrll * NSIDE - ix - iy - 1;
    bool north = jr < NSIDE;
    bool south = jr > 3 * NSIDE;
    int nr = north ? jr : (south ? 4 * NSIDE - jr : NSIDE);
    const float fact2 = 4.0f / (12.0f * (float)NSIDE * (float)NSIDE);
    const float fact1 = (2.0f * (float)NSIDE) * fact2;
    float nrf = (float)nr;
    float z;
    if (north)      z = 1.0f - nrf * nrf * fact2;
    else if (south) z = nrf * nrf * fact2 - 1.0f;
    else            z = (float)(2 * NSIDE - jr) * fact1;
    int kshift = (north || south) ? 0 : (jr & 1);
    int num = jpll * nr + ix - iy + 1 + kshift;
    int jp = num / 2;                     // trunc toward zero == reference
    if (jp > 4 * nr) jp -= 4 * nr;
    if (jp < 1)      jp += 4 * nr;
    float phi = ((float)jp - ((float)kshift + 1.0f) * 0.5f) * (1.5707963267948966f / nrf);
    float sth = sqrtf((1.0f - z) * (1.0f + z));
    float sp, cp;
    __sincosf(phi, &sp, &cp);
    float3 r;
    r.x = sth * cp;
    r.y = sth * sp;
    r.z = z;
    return r;
}

// ---------- kernel 1: build 4 B/facet code table + tail passthrough outputs ----------
__global__ __launch_bounds__(256)
void build_tail_kernel(const int* __restrict__ corr,
                       const int* __restrict__ f0s,
                       const int* __restrict__ f1s,
                       const float* __restrict__ kps,
                       unsigned* __restrict__ table,
                       float* __restrict__ out,
                       int n0, int n1,
                       int idx0_off, int idx1_off, int kps_off) {
    int i = blockIdx.x * blockDim.x + threadIdx.x;
    if (i < n0) {
        int f0 = f0s[i];
        int j  = corr[i];
        int a = (f0 == 0) ? 0 : f1s[j];      // lut_corr[0]=0 override
        int b = (a == 0) ? 0 : j;            // lut_kpt[0]=0 override
        float sc = kps[b];
        unsigned code = ((unsigned)a << 12) | encode_score(sc);
        table[f0] = code;                    // f0 unique -> race-free
        __builtin_nontemporal_store((float)i, &out[idx0_off + i]);
        __builtin_nontemporal_store((float)j, &out[idx1_off + i]);
    }
    if (i < n1) {
        __builtin_nontemporal_store(kps[i], &out[kps_off + i]);
    }
}

// ---------- kernel 2: COG over groups of 4 children ----------
__global__ __launch_bounds__(256)
void cog_kernel(const vint4* __restrict__ filt4,
                const unsigned* __restrict__ table,
                float* __restrict__ out,
                int P, int score_off) {
    int p = blockIdx.x * blockDim.x + threadIdx.x;
    if (p >= P) return;
    vint4 f = __builtin_nontemporal_load(&filt4[p]);   // streaming: keep out of L2
    unsigned t0 = table[f.x];
    unsigned t1 = table[f.y];
    unsigned t2 = table[f.z];
    unsigned t3 = table[f.w];
    float s0 = decode_score(t0 & 0xFFFu);
    float s1 = decode_score(t1 & 0xFFFu);
    float s2 = decode_score(t2 & 0xFFFu);
    float s3 = decode_score(t3 & 0xFFFu);
    float3 v0 = pix2vec_nest256((int)(t0 >> 12));
    float3 v1 = pix2vec_nest256((int)(t1 >> 12));
    float3 v2 = pix2vec_nest256((int)(t2 >> 12));
    float3 v3 = pix2vec_nest256((int)(t3 >> 12));
    float den = s0 + s1 + s2 + s3;
    float px = s0 * v0.x + s1 * v1.x + s2 * v2.x + s3 * v3.x;
    float py = s0 * v0.y + s1 * v1.y + s2 * v2.y + s3 * v3.y;
    float pz = s0 * v0.z + s1 * v1.z + s2 * v2.z + s3 * v3.z;
    int cnt = (int)(s0 > 0.f) + (int)(s1 > 0.f) + (int)(s2 > 0.f) + (int)(s3 > 0.f);
    float ox = 0.f, oy = 0.f, oz = 0.f, osc = 0.f;
    if (den != 0.f) {
        float inv = 1.0f / den;
        ox = px * inv; oy = py * inv; oz = pz * inv;
        float rcp = (cnt == 1) ? 1.f : (cnt == 2) ? 0.5f : (cnt == 3) ? (1.f / 3.f) : 0.25f;
        osc = den * rcp;
    }
    __builtin_nontemporal_store(ox, &out[3 * p + 0]);
    __builtin_nontemporal_store(oy, &out[3 * p + 1]);
    __builtin_nontemporal_store(oz, &out[3 * p + 2]);
    __builtin_nontemporal_store(osc, &out[score_off + p]);
}

extern "C" void kernel_launch(void* const* d_in, const int* in_sizes, int n_in,
                              void* d_out, int out_size, void* d_ws, size_t ws_size,
                              hipStream_t stream) {
    // inputs: 0 nside | 1 corr [1,N0] | 2 img0_facets [1,N0] | 3 img1_facets [1,N1]
    //         4 filt [M] | 5 keypointScores1 [1,N1]
    const int* corr = (const int*)d_in[1];
    const int* f0s  = (const int*)d_in[2];
    const int* f1s  = (const int*)d_in[3];
    const int* filt = (const int*)d_in[4];
    const float* kps = (const float*)d_in[5];

    const int n0 = in_sizes[1];
    const int n1 = in_sizes[5];
    const int M  = in_sizes[4];
    const int P  = M / 4;

    // output layout (flat float32, reference return order)
    const int score_off = 3 * P;
    const int idx0_off  = 4 * P;
    const int idx1_off  = idx0_off + n0;
    const int kps_off   = idx1_off + n0;

    unsigned* table = (unsigned*)d_ws;               // NFACETS * 4 B = 3.15 MB (< 4 MB L2/XCD)
    float* out = (float*)d_out;

    hipMemsetAsync(d_ws, 0, (size_t)NFACETS * sizeof(unsigned), stream);

    const int b = 256;
    int ntail = (n0 > n1) ? n0 : n1;
    build_tail_kernel<<<(ntail + b - 1) / b, b, 0, stream>>>(corr, f0s, f1s, kps, table, out,
                                                             n0, n1, idx0_off, idx1_off, kps_off);
    cog_kernel<<<(P + b - 1) / b, b, 0, stream>>>((const vint4*)filt, table, out, P, score_off);
}

// Round 4
// 44.146 us; speedup vs baseline: 1.6443x; 1.0115x over previous
//
#include <hip/hip_runtime.h>
#include <hip/hip_bf16.h>

#define NSIDE    256
#define NFACETS  786432          // 12*256*256

typedef int vint4 __attribute__((ext_vector_type(4)));
typedef unsigned uvec4 __attribute__((ext_vector_type(4)));

// ---------- 12-bit mini-float score codec (5-bit exp bias 95, 7-bit mant, RNE) ----------
// Invariant: code==0  <=>  s==0, so the (s>0) predicate and den==0 path match the reference.
__device__ __forceinline__ unsigned encode_score(float s) {
    if (s <= 0.f) return 0u;                    // scores are >= 0
    unsigned u = __float_as_uint(s);
    u += 0x8000u + ((u >> 16) & 1u);            // RNE to 7-bit mantissa
    int e = (int)((u >> 23) & 0xFFu);
    unsigned m = (u >> 16) & 0x7Fu;
    int field = e - 95;                         // e in [96,126] -> [1,31]
    if (field < 1)  { field = 1; m = 0u; }      // clamp tiny (keeps >0)
    if (field > 31) { field = 31; m = 127u; }   // clamp ~1.0 (rounding overflow)
    return ((unsigned)field << 7) | m;
}
__device__ __forceinline__ float decode_score(unsigned c) {
    if (c == 0u) return 0.f;
    unsigned field = (c >> 7) & 0x1Fu;
    unsigned m = c & 0x7Fu;
    return __uint_as_float(((field + 95u) << 23) | (m << 16));
}

// ---------- HEALPix nested pix2vec, nside=256 ----------
__device__ __forceinline__ unsigned compress_bits(unsigned v) {
    v &= 0x55555555u;
    v = (v | (v >> 1)) & 0x33333333u;
    v = (v | (v >> 2)) & 0x0F0F0F0Fu;
    v = (v | (v >> 4)) & 0x00FF00FFu;
    v = (v | (v >> 8)) & 0x0000FFFFu;
    return v;
}

__device__ __forceinline__ float3 pix2vec_nest256(int pix) {
    int face = pix >> 16;                 // npface = 65536
    unsigned ipf = (unsigned)(pix & 0xFFFF);
    int ix = (int)compress_bits(ipf);
    int iy = (int)compress_bits(ipf >> 1);
    int jrll = 2 + (face >> 2);                               // {2,3,4}
    int jpll = 2 * (face & 3) + (((face >> 2) == 1) ? 0 : 1); // {1,3,5,7,0,2,4,6,1,3,5,7}
    int jr = jrll * NSIDE - ix - iy - 1;
    bool north = jr < NSIDE;
    bool south = jr > 3 * NSIDE;
    int nr = north ? jr : (south ? 4 * NSIDE - jr : NSIDE);
    const float fact2 = 4.0f / (12.0f * (float)NSIDE * (float)NSIDE);
    const float fact1 = (2.0f * (float)NSIDE) * fact2;
    float nrf = (float)nr;
    float z;
    if (north)      z = 1.0f - nrf * nrf * fact2;
    else if (south) z = nrf * nrf * fact2 - 1.0f;
    else            z = (float)(2 * NSIDE - jr) * fact1;
    int kshift = (north || south) ? 0 : (jr & 1);
    int num = jpll * nr + ix - iy + 1 + kshift;
    int jp = num / 2;                     // trunc toward zero == reference
    if (jp > 4 * nr) jp -= 4 * nr;
    if (jp < 1)      jp += 4 * nr;
    float phi = ((float)jp - ((float)kshift + 1.0f) * 0.5f) * (1.5707963267948966f / nrf);
    float sth = sqrtf((1.0f - z) * (1.0f + z));
    float sp, cp;
    __sincosf(phi, &sp, &cp);
    float3 r;
    r.x = sth * cp;
    r.y = sth * sp;
    r.z = z;
    return r;
}

// ---------- kernel 1: zero the table (replaces slow runtime fill) + tail outputs ----------
__global__ __launch_bounds__(256)
void zero_tail_kernel(uvec4* __restrict__ table4,
                      const int* __restrict__ corr,
                      const float* __restrict__ kps,
                      float* __restrict__ out,
                      int nwords4, int n0, int n1,
                      int idx0_off, int idx1_off, int kps_off) {
    int i = blockIdx.x * blockDim.x + threadIdx.x;
    if (i < nwords4) {
        uvec4 z = {0u, 0u, 0u, 0u};
        table4[i] = z;                    // normal store: prime L2 with table lines
    }
    if (i < n0) {
        __builtin_nontemporal_store((float)i, &out[idx0_off + i]);
        __builtin_nontemporal_store((float)corr[i], &out[idx1_off + i]);
    }
    if (i < n1) {
        __builtin_nontemporal_store(kps[i], &out[kps_off + i]);
    }
}

// ---------- kernel 2: scatter per-facet codes ----------
__global__ __launch_bounds__(256)
void build_kernel(const int* __restrict__ corr,
                  const int* __restrict__ f0s,
                  const int* __restrict__ f1s,
                  const float* __restrict__ kps,
                  unsigned* __restrict__ table,
                  int n0) {
    int i = blockIdx.x * blockDim.x + threadIdx.x;
    if (i >= n0) return;
    int f0 = f0s[i];
    int j  = corr[i];
    int a = (f0 == 0) ? 0 : f1s[j];      // lut_corr[0]=0 override
    int b = (a == 0) ? 0 : j;            // lut_kpt[0]=0 override
    float sc = kps[b];
    unsigned code = ((unsigned)a << 12) | encode_score(sc);
    table[f0] = code;                    // f0 unique -> race-free
}

// ---------- kernel 3: COG over groups of 4 children ----------
__global__ __launch_bounds__(256)
void cog_kernel(const vint4* __restrict__ filt4,
                const unsigned* __restrict__ table,
                float* __restrict__ out,
                int P, int score_off) {
    int p = blockIdx.x * blockDim.x + threadIdx.x;
    if (p >= P) return;
    vint4 f = __builtin_nontemporal_load(&filt4[p]);   // streaming: keep out of L2
    unsigned t0 = table[f.x];
    unsigned t1 = table[f.y];
    unsigned t2 = table[f.z];
    unsigned t3 = table[f.w];
    float s0 = decode_score(t0 & 0xFFFu);
    float s1 = decode_score(t1 & 0xFFFu);
    float s2 = decode_score(t2 & 0xFFFu);
    float s3 = decode_score(t3 & 0xFFFu);
    float3 v0 = pix2vec_nest256((int)(t0 >> 12));
    float3 v1 = pix2vec_nest256((int)(t1 >> 12));
    float3 v2 = pix2vec_nest256((int)(t2 >> 12));
    float3 v3 = pix2vec_nest256((int)(t3 >> 12));
    float den = s0 + s1 + s2 + s3;
    float px = s0 * v0.x + s1 * v1.x + s2 * v2.x + s3 * v3.x;
    float py = s0 * v0.y + s1 * v1.y + s2 * v2.y + s3 * v3.y;
    float pz = s0 * v0.z + s1 * v1.z + s2 * v2.z + s3 * v3.z;
    int cnt = (int)(s0 > 0.f) + (int)(s1 > 0.f) + (int)(s2 > 0.f) + (int)(s3 > 0.f);
    float ox = 0.f, oy = 0.f, oz = 0.f, osc = 0.f;
    if (den != 0.f) {
        float inv = 1.0f / den;
        ox = px * inv; oy = py * inv; oz = pz * inv;
        float rcp = (cnt == 1) ? 1.f : (cnt == 2) ? 0.5f : (cnt == 3) ? (1.f / 3.f) : 0.25f;
        osc = den * rcp;
    }
    __builtin_nontemporal_store(ox, &out[3 * p + 0]);
    __builtin_nontemporal_store(oy, &out[3 * p + 1]);
    __builtin_nontemporal_store(oz, &out[3 * p + 2]);
    __builtin_nontemporal_store(osc, &out[score_off + p]);
}

extern "C" void kernel_launch(void* const* d_in, const int* in_sizes, int n_in,
                              void* d_out, int out_size, void* d_ws, size_t ws_size,
                              hipStream_t stream) {
    // inputs: 0 nside | 1 corr [1,N0] | 2 img0_facets [1,N0] | 3 img1_facets [1,N1]
    //         4 filt [M] | 5 keypointScores1 [1,N1]
    const int* corr = (const int*)d_in[1];
    const int* f0s  = (const int*)d_in[2];
    const int* f1s  = (const int*)d_in[3];
    const int* filt = (const int*)d_in[4];
    const float* kps = (const float*)d_in[5];

    const int n0 = in_sizes[1];
    const int n1 = in_sizes[5];
    const int M  = in_sizes[4];
    const int P  = M / 4;

    // output layout (flat float32, reference return order)
    const int score_off = 3 * P;
    const int idx0_off  = 4 * P;
    const int idx1_off  = idx0_off + n0;
    const int kps_off   = idx1_off + n0;

    unsigned* table = (unsigned*)d_ws;               // NFACETS * 4 B = 3.15 MB (< 4 MB L2/XCD)
    float* out = (float*)d_out;

    const int b = 256;
    const int nwords4 = NFACETS / 4;                 // 196608 uint4 stores
    int nmax = nwords4;
    if (n0 > nmax) nmax = n0;
    if (n1 > nmax) nmax = n1;

    zero_tail_kernel<<<(nmax + b - 1) / b, b, 0, stream>>>((uvec4*)table, corr, kps, out,
                                                           nwords4, n0, n1,
                                                           idx0_off, idx1_off, kps_off);
    build_kernel<<<(n0 + b - 1) / b, b, 0, stream>>>(corr, f0s, f1s, kps, table, n0);
    cog_kernel<<<(P + b - 1) / b, b, 0, stream>>>((const vint4*)filt, table, out, P, score_off);
}